// Round 23
// baseline (153.684 us; speedup 1.0000x reference)
//
#include <hip/hip_runtime.h>

typedef float f32x4  __attribute__((ext_vector_type(4)));
typedef float f32x16 __attribute__((ext_vector_type(16)));
typedef short s16x8  __attribute__((ext_vector_type(8)));
typedef unsigned short u16x4 __attribute__((ext_vector_type(4)));
typedef unsigned u32x4 __attribute__((ext_vector_type(4)));
typedef unsigned short u16;

#define NB 8
#define SEQ 1024
#define CIN 512
#define NH 8
#define DK 64
#define MROWS (NB*SEQ)

__device__ __forceinline__ u16 bf16_of(float f) {
  unsigned u = __builtin_bit_cast(unsigned, f);
  u += 0x7fffu + ((u >> 16) & 1u);           // RTNE
  return (u16)(u >> 16);
}
__device__ __forceinline__ float f32_of(u16 b) {
  unsigned u = ((unsigned)b) << 16;
  return __builtin_bit_cast(float, u);
}

// ================= layouts =================
// QF/KF (frags for 32x32x16): [n][h][G(32)][s(4)][L(64)][e(8)] u16
// VF: [n][h][u(64)][dt(2)][L(64)][e(8)] u16
// rg: [n][h][q] f32 rinv
// cs: [n][h][qg(32)][dt(2)][rq(4)][L(64)][j(4)] f32 (scaled ctx)

// ---------------- QKV projection (bf16 MFMA, X split hi/lo) ----------------
#define BM 128
#define BN 128
#define BK 32
#define LDP 40
#define TP  136

__global__ __launch_bounds__(256, 2)
void proj_kernel(const float* __restrict__ x,
                 const float* __restrict__ wq, const float* __restrict__ bq,
                 const float* __restrict__ wk, const float* __restrict__ bk,
                 const float* __restrict__ wv, const float* __restrict__ bv,
                 u16* __restrict__ qht, u16* __restrict__ qlt,
                 u16* __restrict__ kf_, u16* __restrict__ vf_)
{
  __shared__ __align__(16) u16 smem[128 * TP];
  u16 (*Ah)[LDP] = (u16(*)[LDP])(smem);
  u16 (*Al)[LDP] = (u16(*)[LDP])(smem + 128*LDP);
  u16 (*Bw)[LDP] = (u16(*)[LDP])(smem + 256*LDP);

  const int tid  = threadIdx.x;
  const int wid  = tid >> 6, lane = tid & 63;
  const int g    = lane >> 4, li  = lane & 15;
  const int m0   = blockIdx.x * BM;
  const int n0   = blockIdx.y * BN;
  const int z    = blockIdx.z;

  const float* w    = (z == 0) ? wq : (z == 1) ? wk : wv;
  const float* bias = (z == 0) ? bq : (z == 1) ? bk : bv;

  const int wm = wid >> 1, wn = wid & 1;

  f32x4 acc[4][4];
  #pragma unroll
  for (int i = 0; i < 4; i++)
    #pragma unroll
    for (int j = 0; j < 4; j++)
      acc[i][j] = f32x4{0.f, 0.f, 0.f, 0.f};

  const int srow  = tid >> 1;
  const int shalf = (tid & 1) * 16;

  for (int k0 = 0; k0 < CIN; k0 += BK) {
    __syncthreads();
    {
      const float* ax = x + (size_t)(m0 + srow) * CIN + k0 + shalf;
      #pragma unroll
      for (int c = 0; c < 4; c++) {
        f32x4 v = *(const f32x4*)(ax + c*4);
        u16x4 hv, lv;
        #pragma unroll
        for (int e = 0; e < 4; e++) {
          u16 h = bf16_of(v[e]);
          hv[e] = h;
          lv[e] = bf16_of(v[e] - f32_of(h));
        }
        *(u16x4*)&Ah[srow][shalf + c*4] = hv;
        *(u16x4*)&Al[srow][shalf + c*4] = lv;
      }
      const float* bx = w + (size_t)(n0 + srow) * CIN + k0 + shalf;
      #pragma unroll
      for (int c = 0; c < 4; c++) {
        f32x4 v = *(const f32x4*)(bx + c*4);
        u16x4 hv;
        #pragma unroll
        for (int e = 0; e < 4; e++) hv[e] = bf16_of(v[e]);
        *(u16x4*)&Bw[srow][shalf + c*4] = hv;
      }
    }
    __syncthreads();

    s16x8 af[4], alf[4], bfr[4];
    #pragma unroll
    for (int i = 0; i < 4; i++) {
      af[i]  = *(const s16x8*)&Ah[wm*64 + i*16 + li][8*g];
      alf[i] = *(const s16x8*)&Al[wm*64 + i*16 + li][8*g];
      bfr[i] = *(const s16x8*)&Bw[wn*64 + i*16 + li][8*g];
    }
    #pragma unroll
    for (int i = 0; i < 4; i++)
      #pragma unroll
      for (int j = 0; j < 4; j++) {
        acc[i][j] = __builtin_amdgcn_mfma_f32_16x16x32_bf16(af[i],  bfr[j], acc[i][j], 0, 0, 0);
        acc[i][j] = __builtin_amdgcn_mfma_f32_16x16x32_bf16(alf[i], bfr[j], acc[i][j], 0, 0, 0);
      }
  }

  // ---- epilogues: T[c_local][r_local] then fragment-linear scatters ----
  __syncthreads();
  u16 (*T)[TP] = (u16(*)[TP])smem;
  const int n    = m0 >> 10;
  const int tok0 = m0 & 1023;

  auto fillT = [&](bool lo) {
    #pragma unroll
    for (int j = 0; j < 4; j++) {
      const int cl = wn*64 + j*16 + li;
      const float bv_ = bias[n0 + cl];
      #pragma unroll
      for (int i = 0; i < 4; i++) {
        const int rbase = wm*64 + i*16 + 4*g;
        #pragma unroll
        for (int r = 0; r < 4; r++) {
          float y = acc[i][j][r] + bv_;
          u16 hi = bf16_of(y);
          T[cl][rbase + r] = lo ? bf16_of(y - f32_of(hi)) : hi;
        }
      }
    }
  };

  auto scatterF = [&](u16* __restrict__ dst) {
    const int s = n0 >> 7;
    #pragma unroll
    for (int it = 0; it < 8; it++) {
      const int chunk = tid + 256*it;
      const int h   = chunk >> 8;
      const int rem = chunk & 255;
      const int kgl = rem >> 6;
      const int L   = rem & 63;
      const int hi  = L >> 5, l31 = L & 31;
      s16x8 o;
      #pragma unroll
      for (int e = 0; e < 8; e++)
        o[e] = (short)T[64*hi + 8*e + h][32*kgl + l31];
      *(s16x8*)&dst[((((size_t)(n*NH + h))*32 + (tok0 >> 5) + kgl)*4 + s)*512 + L*8] = o;
    }
  };

  if (z == 0) {
    fillT(false); __syncthreads(); scatterF(qht);
    __syncthreads();
    fillT(true);  __syncthreads(); scatterF(qlt);
  } else if (z == 1) {
    fillT(false); __syncthreads(); scatterF(kf_);
  } else {
    fillT(false); __syncthreads();
    const int dt = n0 >> 8;
    const int dhb = (n0 >> 7) & 1;
    #pragma unroll
    for (int it = 0; it < 8; it++) {
      const int chunk = tid + 256*it;
      const int h   = chunk >> 8;
      const int rem = chunk & 255;
      const int ul  = rem >> 5;
      const int Lh  = rem & 31;
      const int hi  = Lh >> 4, Ll = Lh & 15;
      const int L   = 32*hi + 16*dhb + Ll;
      s16x8 o = *(const s16x8*)&T[Ll*8 + h][16*ul + 8*hi];
      *(s16x8*)&vf_[((((size_t)(n*NH + h))*64 + (tok0 >> 4) + ul)*2 + dt)*512 + L*8] = o;
    }
  }
}

// ---------------- pass 1: l + PV, barrier-free direct fragment loads ----------------
__global__ __launch_bounds__(512, 4)
void attn_pass1(const u16* __restrict__ qfh_g, const u16* __restrict__ qfl_g,
                const u16* __restrict__ kf_g, const u16* __restrict__ vf_g,
                float* __restrict__ rg, float* __restrict__ cs_g)
{
  __shared__ float mbuf[8704];                        // 34816 B (merge only)

  const int tid  = threadIdx.x;
  const int wid  = tid >> 6, lane = tid & 63;
  const int hi   = lane >> 5;
  const int kh   = wid >> 2;                          // k-half
  const int qgl  = wid & 3;
  const int bid  = blockIdx.x;
  const int n    = bid >> 6;
  const int h    = (bid >> 3) & 7;
  const int qb   = bid & 7;
  const int qg   = qb*4 + qgl;

  const float SC2 = 0.18033688011112042f;
  const size_t headoff = ((size_t)(n*NH + h))*65536;

  s16x8 qfh[4], qfl[4];
  {
    const size_t qbase = ((size_t)((n*NH + h)*32 + qg))*2048;
    #pragma unroll
    for (int s = 0; s < 4; s++) {
      qfh[s] = *(const s16x8*)(qfh_g + qbase + (size_t)(s*64 + lane)*8);
      qfl[s] = *(const s16x8*)(qfl_g + qbase + (size_t)(s*64 + lane)*8);
    }
  }

  const u16* Kt = kf_g + headoff;
  const u16* Vt = vf_g + headoff;

  float l_ = 0.f;
  f32x16 ctx0, ctx1;
  #pragma unroll
  for (int r = 0; r < 16; r++) { ctx0[r] = 0.f; ctx1[r] = 0.f; }

  for (int t = 0; t < 8; ++t) {                       // 64 tokens/step, this kh half
    const int tt = kh*8 + t;
    #pragma unroll
    for (int kg2 = 0; kg2 < 2; kg2++) {
      const int G = tt*2 + kg2;                       // 32-tok group
      f32x16 acc;
      #pragma unroll
      for (int r = 0; r < 16; r++) acc[r] = 0.f;
      #pragma unroll
      for (int s4 = 0; s4 < 4; s4++) {
        s16x8 kfr = *(const s16x8*)(Kt + ((size_t)G*4 + s4)*512 + (size_t)lane*8);
        acc = __builtin_amdgcn_mfma_f32_32x32x16_bf16(kfr, qfh[s4], acc, 0, 0, 0);
        acc = __builtin_amdgcn_mfma_f32_32x32x16_bf16(kfr, qfl[s4], acc, 0, 0, 0);
      }
      float P[16];
      #pragma unroll
      for (int r = 0; r < 16; r++) { P[r] = __builtin_exp2f(acc[r]*SC2); l_ += P[r]; }
      #pragma unroll
      for (int ul = 0; ul < 2; ul++) {
        const int B = ul*8;
        unsigned a0, a1, b0, b1;
        asm("v_cvt_pk_bf16_f32 %0,%1,%2" : "=v"(a0) : "v"(P[B+0]), "v"(P[B+1]));
        asm("v_cvt_pk_bf16_f32 %0,%1,%2" : "=v"(a1) : "v"(P[B+2]), "v"(P[B+3]));
        asm("v_cvt_pk_bf16_f32 %0,%1,%2" : "=v"(b0) : "v"(P[B+4]), "v"(P[B+5]));
        asm("v_cvt_pk_bf16_f32 %0,%1,%2" : "=v"(b1) : "v"(P[B+6]), "v"(P[B+7]));
        asm volatile("v_permlane32_swap_b32 %0, %1" : "+v"(a0), "+v"(b0));
        asm volatile("v_permlane32_swap_b32 %0, %1" : "+v"(a1), "+v"(b1));
        u32x4 tw; tw[0] = a0; tw[1] = a1; tw[2] = b0; tw[3] = b1;
        s16x8 pf = __builtin_bit_cast(s16x8, tw);
        const int u = G*2 + ul;                       // 16-tok group
        s16x8 vf0 = *(const s16x8*)(Vt + ((size_t)u*2 + 0)*512 + (size_t)lane*8);
        s16x8 vf1 = *(const s16x8*)(Vt + ((size_t)u*2 + 1)*512 + (size_t)lane*8);
        ctx0 = __builtin_amdgcn_mfma_f32_32x32x16_bf16(pf, vf0, ctx0, 0, 0, 0);
        ctx1 = __builtin_amdgcn_mfma_f32_32x32x16_bf16(pf, vf1, ctx1, 0, 0, 0);
      }
    }
  }

  // wave-local l across hi halves
  float lx = l_, ly = l_;
  asm volatile("v_permlane32_swap_b32 %0, %1" : "+v"(lx), "+v"(ly));
  const float lw = lx + ly;

  // cross-half (kh) merge via LDS
  const int mo = (qgl*64 + lane)*34;
  if (kh == 1) {
    #pragma unroll
    for (int r = 0; r < 16; r++) { mbuf[mo + r] = ctx0[r]; mbuf[mo + 16 + r] = ctx1[r]; }
    mbuf[mo + 32] = lw;
  }
  __syncthreads();
  if (kh == 0) {
    #pragma unroll
    for (int r = 0; r < 16; r++) { ctx0[r] += mbuf[mo + r]; ctx1[r] += mbuf[mo + 16 + r]; }
    const float rinv = 1.0f / (lw + mbuf[mo + 32]);
    if (lane < 32)
      rg[((size_t)(n*NH + h))*SEQ + qg*32 + lane] = rinv;

    float rv[16];
    const int hib = hi*16;
    #pragma unroll
    for (int r = 0; r < 16; r++) {
      const int addr = 4*((r&3) + 8*(r>>2)) + hib;
      rv[r] = __builtin_bit_cast(float,
                __builtin_amdgcn_ds_bpermute(addr, __builtin_bit_cast(int, rinv)));
    }

    float* csb = cs_g + ((size_t)((n*NH + h)*32 + qg))*2048;
    #pragma unroll
    for (int rq = 0; rq < 4; rq++) {
      f32x4 v0, v1;
      #pragma unroll
      for (int j = 0; j < 4; j++) {
        v0[j] = ctx0[4*rq + j] * rv[4*rq + j];
        v1[j] = ctx1[4*rq + j] * rv[4*rq + j];
      }
      *(f32x4*)&csb[((0*4 + rq)*64 + lane)*4] = v0;
      *(f32x4*)&csb[((1*4 + rq)*64 + lane)*4] = v1;
    }
  }
}

// ---------------- pass 2: recompute QK, write normalized attn (f32) ----------------
// block = (n, qg, k-quarter); 8 waves = 8 heads; bf16 dbuf Plds (34.8 KB -> 4 blocks/CU);
// lgkm-only barrier; dense 1KB-per-instruction stores. 1024 blocks -> 32 waves/CU.
__global__ __launch_bounds__(512, 4)
void attn_write(const u16* __restrict__ qfh_g, const u16* __restrict__ qfl_g,
                const u16* __restrict__ kf_g, const float* __restrict__ rg,
                const float* __restrict__ cs, float* __restrict__ ctx_out,
                float* __restrict__ attn_out)
{
  __shared__ u16 Plds[2][NH][32][34];                // 34816 B

  const int tid  = threadIdx.x;
  const int h    = tid >> 6;                         // wave = head (compute) / row group (store)
  const int lane = tid & 63;
  const int hi   = lane >> 5, l31 = lane & 31;
  const int bid  = blockIdx.x;
  const int n    = bid >> 7;
  const int qg   = (bid >> 2) & 31;
  const int kq   = bid & 3;                          // 256-k quarter

  const float SC2 = 0.18033688011112042f;

  s16x8 qfh[4], qfl[4];
  {
    const size_t qbase = ((size_t)((n*NH + h)*32 + qg))*2048;
    #pragma unroll
    for (int s = 0; s < 4; s++) {
      qfh[s] = *(const s16x8*)(qfh_g + qbase + (size_t)(s*64 + lane)*8);
      qfl[s] = *(const s16x8*)(qfl_g + qbase + (size_t)(s*64 + lane)*8);
    }
  }
  const float rinv = rg[((size_t)(n*NH + h))*SEQ + qg*32 + l31];
  const u16* Kt = kf_g + ((size_t)(n*NH + h))*65536;

  auto computeQK = [&](int t, f32x16& acc) {
    const int G = kq*8 + t;
    #pragma unroll
    for (int r = 0; r < 16; r++) acc[r] = 0.f;
    #pragma unroll
    for (int s = 0; s < 4; s++) {
      s16x8 kfr = *(const s16x8*)(Kt + ((size_t)G*4 + s)*512 + (size_t)lane*8);
      acc = __builtin_amdgcn_mfma_f32_32x32x16_bf16(kfr, qfh[s], acc, 0, 0, 0);
      acc = __builtin_amdgcn_mfma_f32_32x32x16_bf16(kfr, qfl[s], acc, 0, 0, 0);
    }
  };
  auto scatterP = [&](const f32x16& acc, int buf) {
    #pragma unroll
    for (int r = 0; r < 16; r++) {
      const int krow = (r&3) + 8*(r>>2) + 4*hi;
      Plds[buf][h][krow][l31] = bf16_of(__builtin_exp2f(acc[r]*SC2) * rinv);
    }
  };
  // Dense store: instruction i writes q-row 4h+i entirely; lane l covers
  // float offset l*4 of the row's 1KB slice (k = l>>1, heads = (l&1)*4..+3).
  auto storeStep = [&](int t, int buf) {
    const int kl = lane >> 1;
    const int h0 = (lane & 1) * 4;
    const int k0 = kq*256 + t*32;
    #pragma unroll
    for (int i = 0; i < 4; i++) {
      const int q32 = h*4 + i;
      f32x4 v;
      #pragma unroll
      for (int j = 0; j < 4; j++)
        v[j] = f32_of(Plds[buf][h0 + j][kl][q32]);
      *(f32x4*)(attn_out + ((size_t)(n*SEQ + qg*32 + q32)*SEQ + k0 + kl)*NH + h0) = v;
    }
  };
  // LDS-only fence (no vmcnt drain)
  auto ldsBarrier = [&]() {
    asm volatile("s_waitcnt lgkmcnt(0)" ::: "memory");
    __builtin_amdgcn_s_barrier();
  };

  f32x16 acc;
  computeQK(0, acc);
  scatterP(acc, 0);
  ldsBarrier();

  for (int t = 0; t < 8; ++t) {
    if (t < 7) computeQK(t + 1, acc);      // K loads + MFMA (register-only)
    storeStep(t, t & 1);                   // dense 1KB-per-instruction stores
    if (t < 7) scatterP(acc, (t + 1) & 1);
    ldsBarrier();
  }

  // ---- ctx merge from cs on kq==0 blocks: flat-indexed, dense 16B/lane ----
  if (kq == 0) {
    #pragma unroll
    for (int i = 0; i < 8; i++) {
      const int chunk = i*512 + tid;        // 0..4095 (64 KB region / 16 B)
      const int q2  = chunk >> 7;           // 0..31
      const int fo  = (chunk & 127) * 4;    // float offset in row
      const int h0  = fo & 7;               // 0 or 4
      const int d   = fo >> 3;              // 0..63
      const int dt  = d >> 5;
      const int rq  = q2 >> 3;
      const int hi2 = (q2 >> 2) & 1;
      const int jj  = q2 & 3;
      const int L   = hi2*32 + (d & 31);
      f32x4 v;
      #pragma unroll
      for (int j = 0; j < 4; j++)
        v[j] = cs[((size_t)((n*NH + h0 + j)*32 + qg))*2048 + ((dt*4 + rq)*64 + L)*4 + jj];
      *(f32x4*)(ctx_out + ((size_t)(n*SEQ + qg*32 + q2))*CIN + fo) = v;
    }
  }
}

// ---------------- launch ----------------
extern "C" void kernel_launch(void* const* d_in, const int* in_sizes, int n_in,
                              void* d_out, int out_size, void* d_ws, size_t ws_size,
                              hipStream_t stream) {
  const float* x  = (const float*)d_in[0];
  const float* wq = (const float*)d_in[1];
  const float* bq = (const float*)d_in[2];
  const float* wk = (const float*)d_in[3];
  const float* bk = (const float*)d_in[4];
  const float* wv = (const float*)d_in[5];
  const float* bv = (const float*)d_in[6];

  float* ctx_out  = (float*)d_out;
  float* attn_out = ctx_out + (size_t)NB * SEQ * CIN;

  const size_t qkv_elems = (size_t)MROWS * CIN;
  u16* qht = (u16*)d_ws;
  u16* qlt = qht + qkv_elems;
  u16* kf  = qlt + qkv_elems;
  u16* vf  = kf  + qkv_elems;
  float* rg = (float*)(vf + qkv_elems);                     // 256 KB
  float* cs = rg + (size_t)NB*NH*SEQ;                       // 16 MB

  dim3 pg_(MROWS / BM, CIN / BN, 3);
  proj_kernel<<<pg_, 256, 0, stream>>>(x, wq, bq, wk, bk, wv, bv, qht, qlt, kf, vf);

  attn_pass1<<<dim3(NB * NH * 8), 512, 0, stream>>>(qht, qlt, kf, vf, rg, cs);

  attn_write<<<dim3(NB * 32 * 4), 512, 0, stream>>>(qht, qlt, kf, rg, cs, ctx_out, attn_out);
}

// Round 24
// 148.231 us; speedup vs baseline: 1.0368x; 1.0368x over previous
//
#include <hip/hip_runtime.h>

typedef float f32x4  __attribute__((ext_vector_type(4)));
typedef float f32x16 __attribute__((ext_vector_type(16)));
typedef short s16x8  __attribute__((ext_vector_type(8)));
typedef unsigned short u16x4 __attribute__((ext_vector_type(4)));
typedef unsigned u32x4 __attribute__((ext_vector_type(4)));
typedef unsigned short u16;

#define NB 8
#define SEQ 1024
#define CIN 512
#define NH 8
#define DK 64
#define MROWS (NB*SEQ)

__device__ __forceinline__ u16 bf16_of(float f) {
  unsigned u = __builtin_bit_cast(unsigned, f);
  u += 0x7fffu + ((u >> 16) & 1u);           // RTNE
  return (u16)(u >> 16);
}
__device__ __forceinline__ float f32_of(u16 b) {
  unsigned u = ((unsigned)b) << 16;
  return __builtin_bit_cast(float, u);
}

// ================= layouts =================
// QF/KF (frags for 32x32x16): [n][h][G(32)][s(4)][L(64)][e(8)] u16
// VF: [n][h][u(64)][dt(2)][L(64)][e(8)] u16
// rg: [n][h][q] f32 rinv
// cs: [n][h][qg(32)][dt(2)][rq(4)][L(64)][j(4)] f32 (scaled ctx)

// ---------------- QKV projection (bf16 MFMA, X split hi/lo) ----------------
#define BM 128
#define BN 128
#define BK 32
#define LDP 40
#define TP  136

__global__ __launch_bounds__(256, 2)
void proj_kernel(const float* __restrict__ x,
                 const float* __restrict__ wq, const float* __restrict__ bq,
                 const float* __restrict__ wk, const float* __restrict__ bk,
                 const float* __restrict__ wv, const float* __restrict__ bv,
                 u16* __restrict__ qht, u16* __restrict__ qlt,
                 u16* __restrict__ kf_, u16* __restrict__ vf_)
{
  __shared__ __align__(16) u16 smem[128 * TP];
  u16 (*Ah)[LDP] = (u16(*)[LDP])(smem);
  u16 (*Al)[LDP] = (u16(*)[LDP])(smem + 128*LDP);
  u16 (*Bw)[LDP] = (u16(*)[LDP])(smem + 256*LDP);

  const int tid  = threadIdx.x;
  const int wid  = tid >> 6, lane = tid & 63;
  const int g    = lane >> 4, li  = lane & 15;
  const int m0   = blockIdx.x * BM;
  const int n0   = blockIdx.y * BN;
  const int z    = blockIdx.z;

  const float* w    = (z == 0) ? wq : (z == 1) ? wk : wv;
  const float* bias = (z == 0) ? bq : (z == 1) ? bk : bv;

  const int wm = wid >> 1, wn = wid & 1;

  f32x4 acc[4][4];
  #pragma unroll
  for (int i = 0; i < 4; i++)
    #pragma unroll
    for (int j = 0; j < 4; j++)
      acc[i][j] = f32x4{0.f, 0.f, 0.f, 0.f};

  const int srow  = tid >> 1;
  const int shalf = (tid & 1) * 16;

  for (int k0 = 0; k0 < CIN; k0 += BK) {
    __syncthreads();
    {
      const float* ax = x + (size_t)(m0 + srow) * CIN + k0 + shalf;
      #pragma unroll
      for (int c = 0; c < 4; c++) {
        f32x4 v = *(const f32x4*)(ax + c*4);
        u16x4 hv, lv;
        #pragma unroll
        for (int e = 0; e < 4; e++) {
          u16 h = bf16_of(v[e]);
          hv[e] = h;
          lv[e] = bf16_of(v[e] - f32_of(h));
        }
        *(u16x4*)&Ah[srow][shalf + c*4] = hv;
        *(u16x4*)&Al[srow][shalf + c*4] = lv;
      }
      const float* bx = w + (size_t)(n0 + srow) * CIN + k0 + shalf;
      #pragma unroll
      for (int c = 0; c < 4; c++) {
        f32x4 v = *(const f32x4*)(bx + c*4);
        u16x4 hv;
        #pragma unroll
        for (int e = 0; e < 4; e++) hv[e] = bf16_of(v[e]);
        *(u16x4*)&Bw[srow][shalf + c*4] = hv;
      }
    }
    __syncthreads();

    s16x8 af[4], alf[4], bfr[4];
    #pragma unroll
    for (int i = 0; i < 4; i++) {
      af[i]  = *(const s16x8*)&Ah[wm*64 + i*16 + li][8*g];
      alf[i] = *(const s16x8*)&Al[wm*64 + i*16 + li][8*g];
      bfr[i] = *(const s16x8*)&Bw[wn*64 + i*16 + li][8*g];
    }
    #pragma unroll
    for (int i = 0; i < 4; i++)
      #pragma unroll
      for (int j = 0; j < 4; j++) {
        acc[i][j] = __builtin_amdgcn_mfma_f32_16x16x32_bf16(af[i],  bfr[j], acc[i][j], 0, 0, 0);
        acc[i][j] = __builtin_amdgcn_mfma_f32_16x16x32_bf16(alf[i], bfr[j], acc[i][j], 0, 0, 0);
      }
  }

  // ---- epilogues: T[c_local][r_local] then fragment-linear scatters ----
  __syncthreads();
  u16 (*T)[TP] = (u16(*)[TP])smem;
  const int n    = m0 >> 10;
  const int tok0 = m0 & 1023;

  auto fillT = [&](bool lo) {
    #pragma unroll
    for (int j = 0; j < 4; j++) {
      const int cl = wn*64 + j*16 + li;
      const float bv_ = bias[n0 + cl];
      #pragma unroll
      for (int i = 0; i < 4; i++) {
        const int rbase = wm*64 + i*16 + 4*g;
        #pragma unroll
        for (int r = 0; r < 4; r++) {
          float y = acc[i][j][r] + bv_;
          u16 hi = bf16_of(y);
          T[cl][rbase + r] = lo ? bf16_of(y - f32_of(hi)) : hi;
        }
      }
    }
  };

  auto scatterF = [&](u16* __restrict__ dst) {
    const int s = n0 >> 7;
    #pragma unroll
    for (int it = 0; it < 8; it++) {
      const int chunk = tid + 256*it;
      const int h   = chunk >> 8;
      const int rem = chunk & 255;
      const int kgl = rem >> 6;
      const int L   = rem & 63;
      const int hi  = L >> 5, l31 = L & 31;
      s16x8 o;
      #pragma unroll
      for (int e = 0; e < 8; e++)
        o[e] = (short)T[64*hi + 8*e + h][32*kgl + l31];
      *(s16x8*)&dst[((((size_t)(n*NH + h))*32 + (tok0 >> 5) + kgl)*4 + s)*512 + L*8] = o;
    }
  };

  if (z == 0) {
    fillT(false); __syncthreads(); scatterF(qht);
    __syncthreads();
    fillT(true);  __syncthreads(); scatterF(qlt);
  } else if (z == 1) {
    fillT(false); __syncthreads(); scatterF(kf_);
  } else {
    fillT(false); __syncthreads();
    const int dt = n0 >> 8;
    const int dhb = (n0 >> 7) & 1;
    #pragma unroll
    for (int it = 0; it < 8; it++) {
      const int chunk = tid + 256*it;
      const int h   = chunk >> 8;
      const int rem = chunk & 255;
      const int ul  = rem >> 5;
      const int Lh  = rem & 31;
      const int hi  = Lh >> 4, Ll = Lh & 15;
      const int L   = 32*hi + 16*dhb + Ll;
      s16x8 o = *(const s16x8*)&T[Ll*8 + h][16*ul + 8*hi];
      *(s16x8*)&vf_[((((size_t)(n*NH + h))*64 + (tok0 >> 4) + ul)*2 + dt)*512 + L*8] = o;
    }
  }
}

// ---------------- pass 1: l + PV, barrier-free direct fragment loads ----------------
__global__ __launch_bounds__(512, 4)
void attn_pass1(const u16* __restrict__ qfh_g, const u16* __restrict__ qfl_g,
                const u16* __restrict__ kf_g, const u16* __restrict__ vf_g,
                float* __restrict__ rg, float* __restrict__ cs_g)
{
  __shared__ float mbuf[8704];                        // 34816 B (merge only)

  const int tid  = threadIdx.x;
  const int wid  = tid >> 6, lane = tid & 63;
  const int hi   = lane >> 5;
  const int kh   = wid >> 2;                          // k-half
  const int qgl  = wid & 3;
  const int bid  = blockIdx.x;
  const int n    = bid >> 6;
  const int h    = (bid >> 3) & 7;
  const int qb   = bid & 7;
  const int qg   = qb*4 + qgl;

  const float SC2 = 0.18033688011112042f;
  const size_t headoff = ((size_t)(n*NH + h))*65536;

  s16x8 qfh[4], qfl[4];
  {
    const size_t qbase = ((size_t)((n*NH + h)*32 + qg))*2048;
    #pragma unroll
    for (int s = 0; s < 4; s++) {
      qfh[s] = *(const s16x8*)(qfh_g + qbase + (size_t)(s*64 + lane)*8);
      qfl[s] = *(const s16x8*)(qfl_g + qbase + (size_t)(s*64 + lane)*8);
    }
  }

  const u16* Kt = kf_g + headoff;
  const u16* Vt = vf_g + headoff;

  float l_ = 0.f;
  f32x16 ctx0, ctx1;
  #pragma unroll
  for (int r = 0; r < 16; r++) { ctx0[r] = 0.f; ctx1[r] = 0.f; }

  for (int t = 0; t < 8; ++t) {                       // 64 tokens/step, this kh half
    const int tt = kh*8 + t;
    #pragma unroll
    for (int kg2 = 0; kg2 < 2; kg2++) {
      const int G = tt*2 + kg2;                       // 32-tok group
      f32x16 acc;
      #pragma unroll
      for (int r = 0; r < 16; r++) acc[r] = 0.f;
      #pragma unroll
      for (int s4 = 0; s4 < 4; s4++) {
        s16x8 kfr = *(const s16x8*)(Kt + ((size_t)G*4 + s4)*512 + (size_t)lane*8);
        acc = __builtin_amdgcn_mfma_f32_32x32x16_bf16(kfr, qfh[s4], acc, 0, 0, 0);
        acc = __builtin_amdgcn_mfma_f32_32x32x16_bf16(kfr, qfl[s4], acc, 0, 0, 0);
      }
      float P[16];
      #pragma unroll
      for (int r = 0; r < 16; r++) { P[r] = __builtin_exp2f(acc[r]*SC2); l_ += P[r]; }
      #pragma unroll
      for (int ul = 0; ul < 2; ul++) {
        const int B = ul*8;
        unsigned a0, a1, b0, b1;
        asm("v_cvt_pk_bf16_f32 %0,%1,%2" : "=v"(a0) : "v"(P[B+0]), "v"(P[B+1]));
        asm("v_cvt_pk_bf16_f32 %0,%1,%2" : "=v"(a1) : "v"(P[B+2]), "v"(P[B+3]));
        asm("v_cvt_pk_bf16_f32 %0,%1,%2" : "=v"(b0) : "v"(P[B+4]), "v"(P[B+5]));
        asm("v_cvt_pk_bf16_f32 %0,%1,%2" : "=v"(b1) : "v"(P[B+6]), "v"(P[B+7]));
        asm volatile("v_permlane32_swap_b32 %0, %1" : "+v"(a0), "+v"(b0));
        asm volatile("v_permlane32_swap_b32 %0, %1" : "+v"(a1), "+v"(b1));
        u32x4 tw; tw[0] = a0; tw[1] = a1; tw[2] = b0; tw[3] = b1;
        s16x8 pf = __builtin_bit_cast(s16x8, tw);
        const int u = G*2 + ul;                       // 16-tok group
        s16x8 vf0 = *(const s16x8*)(Vt + ((size_t)u*2 + 0)*512 + (size_t)lane*8);
        s16x8 vf1 = *(const s16x8*)(Vt + ((size_t)u*2 + 1)*512 + (size_t)lane*8);
        ctx0 = __builtin_amdgcn_mfma_f32_32x32x16_bf16(pf, vf0, ctx0, 0, 0, 0);
        ctx1 = __builtin_amdgcn_mfma_f32_32x32x16_bf16(pf, vf1, ctx1, 0, 0, 0);
      }
    }
  }

  // wave-local l across hi halves
  float lx = l_, ly = l_;
  asm volatile("v_permlane32_swap_b32 %0, %1" : "+v"(lx), "+v"(ly));
  const float lw = lx + ly;

  // cross-half (kh) merge via LDS
  const int mo = (qgl*64 + lane)*34;
  if (kh == 1) {
    #pragma unroll
    for (int r = 0; r < 16; r++) { mbuf[mo + r] = ctx0[r]; mbuf[mo + 16 + r] = ctx1[r]; }
    mbuf[mo + 32] = lw;
  }
  __syncthreads();
  if (kh == 0) {
    #pragma unroll
    for (int r = 0; r < 16; r++) { ctx0[r] += mbuf[mo + r]; ctx1[r] += mbuf[mo + 16 + r]; }
    const float rinv = 1.0f / (lw + mbuf[mo + 32]);
    if (lane < 32)
      rg[((size_t)(n*NH + h))*SEQ + qg*32 + lane] = rinv;

    float rv[16];
    const int hib = hi*16;
    #pragma unroll
    for (int r = 0; r < 16; r++) {
      const int addr = 4*((r&3) + 8*(r>>2)) + hib;
      rv[r] = __builtin_bit_cast(float,
                __builtin_amdgcn_ds_bpermute(addr, __builtin_bit_cast(int, rinv)));
    }

    float* csb = cs_g + ((size_t)((n*NH + h)*32 + qg))*2048;
    #pragma unroll
    for (int rq = 0; rq < 4; rq++) {
      f32x4 v0, v1;
      #pragma unroll
      for (int j = 0; j < 4; j++) {
        v0[j] = ctx0[4*rq + j] * rv[4*rq + j];
        v1[j] = ctx1[4*rq + j] * rv[4*rq + j];
      }
      *(f32x4*)&csb[((0*4 + rq)*64 + lane)*4] = v0;
      *(f32x4*)&csb[((1*4 + rq)*64 + lane)*4] = v1;
    }
  }
}

// ---------------- pass 2: recompute QK (Q-hi only), write normalized attn (f32) ----------------
// block = (n, qg, k-half); 8 waves = 8 heads; f32 dbuf Plds; lgkm-only barrier;
// dense 1KB-per-instruction stores; rinv folded into the exponent.
__global__ __launch_bounds__(512, 4)
void attn_write(const u16* __restrict__ qfh_g,
                const u16* __restrict__ kf_g, const float* __restrict__ rg,
                const float* __restrict__ cs, float* __restrict__ ctx_out,
                float* __restrict__ attn_out)
{
  __shared__ float Plds[2][NH][32][33];              // 67584 B

  const int tid  = threadIdx.x;
  const int h    = tid >> 6;                         // wave = head (compute) / row group (store)
  const int lane = tid & 63;
  const int hi   = lane >> 5, l31 = lane & 31;
  const int bid  = blockIdx.x;
  const int n    = bid >> 6;
  const int qg   = (bid >> 1) & 31;
  const int kh   = bid & 1;

  const float SC2 = 0.18033688011112042f;

  s16x8 qfh[4];
  {
    const size_t qbase = ((size_t)((n*NH + h)*32 + qg))*2048;
    #pragma unroll
    for (int s = 0; s < 4; s++)
      qfh[s] = *(const s16x8*)(qfh_g + qbase + (size_t)(s*64 + lane)*8);
  }
  const float rinv = rg[((size_t)(n*NH + h))*SEQ + qg*32 + l31];
  const float lb = __log2f(rinv);                    // fold normalization into exponent
  const u16* Kt = kf_g + ((size_t)(n*NH + h))*65536;

  auto computeQK = [&](int t, f32x16& acc) {
    const int G = kh*16 + t;
    #pragma unroll
    for (int r = 0; r < 16; r++) acc[r] = 0.f;
    #pragma unroll
    for (int s = 0; s < 4; s++) {
      s16x8 kfr = *(const s16x8*)(Kt + ((size_t)G*4 + s)*512 + (size_t)lane*8);
      acc = __builtin_amdgcn_mfma_f32_32x32x16_bf16(kfr, qfh[s], acc, 0, 0, 0);
    }
  };
  auto scatterP = [&](const f32x16& acc, int buf) {
    #pragma unroll
    for (int r = 0; r < 16; r++) {
      const int krow = (r&3) + 8*(r>>2) + 4*hi;
      Plds[buf][h][krow][l31] = __builtin_exp2f(__builtin_fmaf(acc[r], SC2, lb));
    }
  };
  // Dense store: instruction i writes q-row 4h+i entirely; lane l covers
  // float offset l*4 of the row's 1KB slice (k = l>>1, heads = (l&1)*4..+3).
  auto storeStep = [&](int t, int buf) {
    const int kl = lane >> 1;
    const int h0 = (lane & 1) * 4;
    const int k0 = kh*512 + t*32;
    #pragma unroll
    for (int i = 0; i < 4; i++) {
      const int q32 = h*4 + i;
      f32x4 v;
      #pragma unroll
      for (int j = 0; j < 4; j++)
        v[j] = Plds[buf][h0 + j][kl][q32];
      *(f32x4*)(attn_out + ((size_t)(n*SEQ + qg*32 + q32)*SEQ + k0 + kl)*NH + h0) = v;
    }
  };
  // LDS-only fence (no vmcnt drain)
  auto ldsBarrier = [&]() {
    asm volatile("s_waitcnt lgkmcnt(0)" ::: "memory");
    __builtin_amdgcn_s_barrier();
  };

  f32x16 acc;
  computeQK(0, acc);
  scatterP(acc, 0);
  ldsBarrier();

  for (int t = 0; t < 16; ++t) {
    if (t < 15) computeQK(t + 1, acc);     // K loads + MFMA (register-only)
    storeStep(t, t & 1);                   // dense 1KB-per-instruction stores
    if (t < 15) scatterP(acc, (t + 1) & 1);
    ldsBarrier();
  }

  // ---- ctx merge from cs on kh==0 blocks: flat-indexed, dense 16B/lane ----
  if (kh == 0) {
    #pragma unroll
    for (int i = 0; i < 8; i++) {
      const int chunk = i*512 + tid;        // 0..4095 (64 KB region / 16 B)
      const int q2  = chunk >> 7;           // 0..31
      const int fo  = (chunk & 127) * 4;    // float offset in row
      const int h0  = fo & 7;               // 0 or 4
      const int d   = fo >> 3;              // 0..63
      const int dt  = d >> 5;
      const int rq  = q2 >> 3;
      const int hi2 = (q2 >> 2) & 1;
      const int jj  = q2 & 3;
      const int L   = hi2*32 + (d & 31);
      f32x4 v;
      #pragma unroll
      for (int j = 0; j < 4; j++)
        v[j] = cs[((size_t)((n*NH + h0 + j)*32 + qg))*2048 + ((dt*4 + rq)*64 + L)*4 + jj];
      *(f32x4*)(ctx_out + ((size_t)(n*SEQ + qg*32 + q2))*CIN + fo) = v;
    }
  }
}

// ---------------- launch ----------------
extern "C" void kernel_launch(void* const* d_in, const int* in_sizes, int n_in,
                              void* d_out, int out_size, void* d_ws, size_t ws_size,
                              hipStream_t stream) {
  const float* x  = (const float*)d_in[0];
  const float* wq = (const float*)d_in[1];
  const float* bq = (const float*)d_in[2];
  const float* wk = (const float*)d_in[3];
  const float* bk = (const float*)d_in[4];
  const float* wv = (const float*)d_in[5];
  const float* bv = (const float*)d_in[6];

  float* ctx_out  = (float*)d_out;
  float* attn_out = ctx_out + (size_t)NB * SEQ * CIN;

  const size_t qkv_elems = (size_t)MROWS * CIN;
  u16* qht = (u16*)d_ws;
  u16* qlt = qht + qkv_elems;
  u16* kf  = qlt + qkv_elems;
  u16* vf  = kf  + qkv_elems;
  float* rg = (float*)(vf + qkv_elems);                     // 256 KB
  float* cs = rg + (size_t)NB*NH*SEQ;                       // 16 MB

  dim3 pg_(MROWS / BM, CIN / BN, 3);
  proj_kernel<<<pg_, 256, 0, stream>>>(x, wq, bq, wk, bk, wv, bv, qht, qlt, kf, vf);

  attn_pass1<<<dim3(NB * NH * 8), 512, 0, stream>>>(qht, qlt, kf, vf, rg, cs);

  attn_write<<<dim3(NB * 32 * 2), 512, 0, stream>>>(qht, kf, rg, cs, ctx_out, attn_out);
}

// Round 25
// 138.670 us; speedup vs baseline: 1.1083x; 1.0690x over previous
//
#include <hip/hip_runtime.h>

typedef float f32x4  __attribute__((ext_vector_type(4)));
typedef float f32x16 __attribute__((ext_vector_type(16)));
typedef short s16x8  __attribute__((ext_vector_type(8)));
typedef unsigned short u16x4 __attribute__((ext_vector_type(4)));
typedef unsigned u32x4 __attribute__((ext_vector_type(4)));
typedef unsigned short u16;

#define NB 8
#define SEQ 1024
#define CIN 512
#define NH 8
#define DK 64
#define MROWS (NB*SEQ)

__device__ __forceinline__ u16 bf16_of(float f) {
  unsigned u = __builtin_bit_cast(unsigned, f);
  u += 0x7fffu + ((u >> 16) & 1u);           // RTNE
  return (u16)(u >> 16);
}
__device__ __forceinline__ float f32_of(u16 b) {
  unsigned u = ((unsigned)b) << 16;
  return __builtin_bit_cast(float, u);
}

// ================= layouts =================
// QF/KF (frags for 32x32x16): [n][h][G(32)][s(4)][L(64)][e(8)] u16
// VF: [n][h][u(64)][dt(2)][L(64)][e(8)] u16
// rg: [n][h][q] f32 rinv
// cs: [n][h][qg(32)][dt(2)][rq(4)][L(64)][j(4)] f32 (scaled ctx)

// ---------------- QKV projection (bf16 MFMA, X split hi/lo) ----------------
#define BM 128
#define BN 128
#define BK 32
#define LDP 40
#define TP  136

__global__ __launch_bounds__(256, 2)
void proj_kernel(const float* __restrict__ x,
                 const float* __restrict__ wq, const float* __restrict__ bq,
                 const float* __restrict__ wk, const float* __restrict__ bk,
                 const float* __restrict__ wv, const float* __restrict__ bv,
                 u16* __restrict__ qht, u16* __restrict__ qlt,
                 u16* __restrict__ kf_, u16* __restrict__ vf_)
{
  __shared__ __align__(16) u16 smem[128 * TP];
  u16 (*Ah)[LDP] = (u16(*)[LDP])(smem);
  u16 (*Al)[LDP] = (u16(*)[LDP])(smem + 128*LDP);
  u16 (*Bw)[LDP] = (u16(*)[LDP])(smem + 256*LDP);

  const int tid  = threadIdx.x;
  const int wid  = tid >> 6, lane = tid & 63;
  const int g    = lane >> 4, li  = lane & 15;
  const int m0   = blockIdx.x * BM;
  const int n0   = blockIdx.y * BN;
  const int z    = blockIdx.z;

  const float* w    = (z == 0) ? wq : (z == 1) ? wk : wv;
  const float* bias = (z == 0) ? bq : (z == 1) ? bk : bv;

  const int wm = wid >> 1, wn = wid & 1;

  f32x4 acc[4][4];
  #pragma unroll
  for (int i = 0; i < 4; i++)
    #pragma unroll
    for (int j = 0; j < 4; j++)
      acc[i][j] = f32x4{0.f, 0.f, 0.f, 0.f};

  const int srow  = tid >> 1;
  const int shalf = (tid & 1) * 16;

  for (int k0 = 0; k0 < CIN; k0 += BK) {
    __syncthreads();
    {
      const float* ax = x + (size_t)(m0 + srow) * CIN + k0 + shalf;
      #pragma unroll
      for (int c = 0; c < 4; c++) {
        f32x4 v = *(const f32x4*)(ax + c*4);
        u16x4 hv, lv;
        #pragma unroll
        for (int e = 0; e < 4; e++) {
          u16 h = bf16_of(v[e]);
          hv[e] = h;
          lv[e] = bf16_of(v[e] - f32_of(h));
        }
        *(u16x4*)&Ah[srow][shalf + c*4] = hv;
        *(u16x4*)&Al[srow][shalf + c*4] = lv;
      }
      const float* bx = w + (size_t)(n0 + srow) * CIN + k0 + shalf;
      #pragma unroll
      for (int c = 0; c < 4; c++) {
        f32x4 v = *(const f32x4*)(bx + c*4);
        u16x4 hv;
        #pragma unroll
        for (int e = 0; e < 4; e++) hv[e] = bf16_of(v[e]);
        *(u16x4*)&Bw[srow][shalf + c*4] = hv;
      }
    }
    __syncthreads();

    s16x8 af[4], alf[4], bfr[4];
    #pragma unroll
    for (int i = 0; i < 4; i++) {
      af[i]  = *(const s16x8*)&Ah[wm*64 + i*16 + li][8*g];
      alf[i] = *(const s16x8*)&Al[wm*64 + i*16 + li][8*g];
      bfr[i] = *(const s16x8*)&Bw[wn*64 + i*16 + li][8*g];
    }
    #pragma unroll
    for (int i = 0; i < 4; i++)
      #pragma unroll
      for (int j = 0; j < 4; j++) {
        acc[i][j] = __builtin_amdgcn_mfma_f32_16x16x32_bf16(af[i],  bfr[j], acc[i][j], 0, 0, 0);
        acc[i][j] = __builtin_amdgcn_mfma_f32_16x16x32_bf16(alf[i], bfr[j], acc[i][j], 0, 0, 0);
      }
  }

  // ---- epilogues: T[c_local][r_local] then fragment-linear scatters ----
  __syncthreads();
  u16 (*T)[TP] = (u16(*)[TP])smem;
  const int n    = m0 >> 10;
  const int tok0 = m0 & 1023;

  auto fillT = [&](bool lo) {
    #pragma unroll
    for (int j = 0; j < 4; j++) {
      const int cl = wn*64 + j*16 + li;
      const float bv_ = bias[n0 + cl];
      #pragma unroll
      for (int i = 0; i < 4; i++) {
        const int rbase = wm*64 + i*16 + 4*g;
        #pragma unroll
        for (int r = 0; r < 4; r++) {
          float y = acc[i][j][r] + bv_;
          u16 hi = bf16_of(y);
          T[cl][rbase + r] = lo ? bf16_of(y - f32_of(hi)) : hi;
        }
      }
    }
  };

  auto scatterF = [&](u16* __restrict__ dst) {
    const int s = n0 >> 7;
    #pragma unroll
    for (int it = 0; it < 8; it++) {
      const int chunk = tid + 256*it;
      const int h   = chunk >> 8;
      const int rem = chunk & 255;
      const int kgl = rem >> 6;
      const int L   = rem & 63;
      const int hi  = L >> 5, l31 = L & 31;
      s16x8 o;
      #pragma unroll
      for (int e = 0; e < 8; e++)
        o[e] = (short)T[64*hi + 8*e + h][32*kgl + l31];
      *(s16x8*)&dst[((((size_t)(n*NH + h))*32 + (tok0 >> 5) + kgl)*4 + s)*512 + L*8] = o;
    }
  };

  if (z == 0) {
    fillT(false); __syncthreads(); scatterF(qht);
    __syncthreads();
    fillT(true);  __syncthreads(); scatterF(qlt);
  } else if (z == 1) {
    fillT(false); __syncthreads(); scatterF(kf_);
  } else {
    fillT(false); __syncthreads();
    const int dt = n0 >> 8;
    const int dhb = (n0 >> 7) & 1;
    #pragma unroll
    for (int it = 0; it < 8; it++) {
      const int chunk = tid + 256*it;
      const int h   = chunk >> 8;
      const int rem = chunk & 255;
      const int ul  = rem >> 5;
      const int Lh  = rem & 31;
      const int hi  = Lh >> 4, Ll = Lh & 15;
      const int L   = 32*hi + 16*dhb + Ll;
      s16x8 o = *(const s16x8*)&T[Ll*8 + h][16*ul + 8*hi];
      *(s16x8*)&vf_[((((size_t)(n*NH + h))*64 + (tok0 >> 4) + ul)*2 + dt)*512 + L*8] = o;
    }
  }
}

// ---------------- pass 1: l + PV, barrier-free direct fragment loads ----------------
__global__ __launch_bounds__(512, 4)
void attn_pass1(const u16* __restrict__ qfh_g, const u16* __restrict__ qfl_g,
                const u16* __restrict__ kf_g, const u16* __restrict__ vf_g,
                float* __restrict__ rg, float* __restrict__ cs_g)
{
  __shared__ float mbuf[8704];                        // 34816 B (merge only)

  const int tid  = threadIdx.x;
  const int wid  = tid >> 6, lane = tid & 63;
  const int hi   = lane >> 5;
  const int kh   = wid >> 2;                          // k-half
  const int qgl  = wid & 3;
  const int bid  = blockIdx.x;
  const int n    = bid >> 6;
  const int h    = (bid >> 3) & 7;
  const int qb   = bid & 7;
  const int qg   = qb*4 + qgl;

  const float SC2 = 0.18033688011112042f;
  const size_t headoff = ((size_t)(n*NH + h))*65536;

  s16x8 qfh[4], qfl[4];
  {
    const size_t qbase = ((size_t)((n*NH + h)*32 + qg))*2048;
    #pragma unroll
    for (int s = 0; s < 4; s++) {
      qfh[s] = *(const s16x8*)(qfh_g + qbase + (size_t)(s*64 + lane)*8);
      qfl[s] = *(const s16x8*)(qfl_g + qbase + (size_t)(s*64 + lane)*8);
    }
  }

  const u16* Kt = kf_g + headoff;
  const u16* Vt = vf_g + headoff;

  float l_ = 0.f;
  f32x16 ctx0, ctx1;
  #pragma unroll
  for (int r = 0; r < 16; r++) { ctx0[r] = 0.f; ctx1[r] = 0.f; }

  for (int t = 0; t < 8; ++t) {                       // 64 tokens/step, this kh half
    const int tt = kh*8 + t;
    #pragma unroll
    for (int kg2 = 0; kg2 < 2; kg2++) {
      const int G = tt*2 + kg2;                       // 32-tok group
      f32x16 acc;
      #pragma unroll
      for (int r = 0; r < 16; r++) acc[r] = 0.f;
      #pragma unroll
      for (int s4 = 0; s4 < 4; s4++) {
        s16x8 kfr = *(const s16x8*)(Kt + ((size_t)G*4 + s4)*512 + (size_t)lane*8);
        acc = __builtin_amdgcn_mfma_f32_32x32x16_bf16(kfr, qfh[s4], acc, 0, 0, 0);
        acc = __builtin_amdgcn_mfma_f32_32x32x16_bf16(kfr, qfl[s4], acc, 0, 0, 0);
      }
      float P[16];
      #pragma unroll
      for (int r = 0; r < 16; r++) { P[r] = __builtin_exp2f(acc[r]*SC2); l_ += P[r]; }
      #pragma unroll
      for (int ul = 0; ul < 2; ul++) {
        const int B = ul*8;
        unsigned a0, a1, b0, b1;
        asm("v_cvt_pk_bf16_f32 %0,%1,%2" : "=v"(a0) : "v"(P[B+0]), "v"(P[B+1]));
        asm("v_cvt_pk_bf16_f32 %0,%1,%2" : "=v"(a1) : "v"(P[B+2]), "v"(P[B+3]));
        asm("v_cvt_pk_bf16_f32 %0,%1,%2" : "=v"(b0) : "v"(P[B+4]), "v"(P[B+5]));
        asm("v_cvt_pk_bf16_f32 %0,%1,%2" : "=v"(b1) : "v"(P[B+6]), "v"(P[B+7]));
        asm volatile("v_permlane32_swap_b32 %0, %1" : "+v"(a0), "+v"(b0));
        asm volatile("v_permlane32_swap_b32 %0, %1" : "+v"(a1), "+v"(b1));
        u32x4 tw; tw[0] = a0; tw[1] = a1; tw[2] = b0; tw[3] = b1;
        s16x8 pf = __builtin_bit_cast(s16x8, tw);
        const int u = G*2 + ul;                       // 16-tok group
        s16x8 vf0 = *(const s16x8*)(Vt + ((size_t)u*2 + 0)*512 + (size_t)lane*8);
        s16x8 vf1 = *(const s16x8*)(Vt + ((size_t)u*2 + 1)*512 + (size_t)lane*8);
        ctx0 = __builtin_amdgcn_mfma_f32_32x32x16_bf16(pf, vf0, ctx0, 0, 0, 0);
        ctx1 = __builtin_amdgcn_mfma_f32_32x32x16_bf16(pf, vf1, ctx1, 0, 0, 0);
      }
    }
  }

  // wave-local l across hi halves
  float lx = l_, ly = l_;
  asm volatile("v_permlane32_swap_b32 %0, %1" : "+v"(lx), "+v"(ly));
  const float lw = lx + ly;

  // cross-half (kh) merge via LDS
  const int mo = (qgl*64 + lane)*34;
  if (kh == 1) {
    #pragma unroll
    for (int r = 0; r < 16; r++) { mbuf[mo + r] = ctx0[r]; mbuf[mo + 16 + r] = ctx1[r]; }
    mbuf[mo + 32] = lw;
  }
  __syncthreads();
  if (kh == 0) {
    #pragma unroll
    for (int r = 0; r < 16; r++) { ctx0[r] += mbuf[mo + r]; ctx1[r] += mbuf[mo + 16 + r]; }
    const float rinv = 1.0f / (lw + mbuf[mo + 32]);
    if (lane < 32)
      rg[((size_t)(n*NH + h))*SEQ + qg*32 + lane] = rinv;

    float rv[16];
    const int hib = hi*16;
    #pragma unroll
    for (int r = 0; r < 16; r++) {
      const int addr = 4*((r&3) + 8*(r>>2)) + hib;
      rv[r] = __builtin_bit_cast(float,
                __builtin_amdgcn_ds_bpermute(addr, __builtin_bit_cast(int, rinv)));
    }

    float* csb = cs_g + ((size_t)((n*NH + h)*32 + qg))*2048;
    #pragma unroll
    for (int rq = 0; rq < 4; rq++) {
      f32x4 v0, v1;
      #pragma unroll
      for (int j = 0; j < 4; j++) {
        v0[j] = ctx0[4*rq + j] * rv[4*rq + j];
        v1[j] = ctx1[4*rq + j] * rv[4*rq + j];
      }
      *(f32x4*)&csb[((0*4 + rq)*64 + lane)*4] = v0;
      *(f32x4*)&csb[((1*4 + rq)*64 + lane)*4] = v1;
    }
  }
}

// ---------------- pass 2: recompute QK (Q-hi only), write normalized attn (f32) ----------------
// block = (n, qg, k-half); 8 waves = 8 heads; f32 dbuf Plds; lgkm-only barrier;
// dense 1KB-per-instruction stores; rinv folded into exponent;
// R25: phase-staggered step ring (adjacent bids offset by 8 steps) to
// desynchronize co-resident blocks' store bursts.
__global__ __launch_bounds__(512, 4)
void attn_write(const u16* __restrict__ qfh_g,
                const u16* __restrict__ kf_g, const float* __restrict__ rg,
                const float* __restrict__ cs, float* __restrict__ ctx_out,
                float* __restrict__ attn_out)
{
  __shared__ float Plds[2][NH][32][33];              // 67584 B

  const int tid  = threadIdx.x;
  const int h    = tid >> 6;                         // wave = head (compute) / row group (store)
  const int lane = tid & 63;
  const int hi   = lane >> 5, l31 = lane & 31;
  const int bid  = blockIdx.x;
  const int n    = bid >> 6;
  const int qg   = (bid >> 1) & 31;
  const int kh   = bid & 1;
  const int t0   = (bid & 1) << 3;                   // phase stagger: 0 or 8

  const float SC2 = 0.18033688011112042f;

  s16x8 qfh[4];
  {
    const size_t qbase = ((size_t)((n*NH + h)*32 + qg))*2048;
    #pragma unroll
    for (int s = 0; s < 4; s++)
      qfh[s] = *(const s16x8*)(qfh_g + qbase + (size_t)(s*64 + lane)*8);
  }
  const float rinv = rg[((size_t)(n*NH + h))*SEQ + qg*32 + l31];
  const float lb = __log2f(rinv);                    // fold normalization into exponent
  const u16* Kt = kf_g + ((size_t)(n*NH + h))*65536;

  auto computeQK = [&](int tt, f32x16& acc) {
    const int G = kh*16 + tt;
    #pragma unroll
    for (int r = 0; r < 16; r++) acc[r] = 0.f;
    #pragma unroll
    for (int s = 0; s < 4; s++) {
      s16x8 kfr = *(const s16x8*)(Kt + ((size_t)G*4 + s)*512 + (size_t)lane*8);
      acc = __builtin_amdgcn_mfma_f32_32x32x16_bf16(kfr, qfh[s], acc, 0, 0, 0);
    }
  };
  auto scatterP = [&](const f32x16& acc, int buf) {
    #pragma unroll
    for (int r = 0; r < 16; r++) {
      const int krow = (r&3) + 8*(r>>2) + 4*hi;
      Plds[buf][h][krow][l31] = __builtin_exp2f(__builtin_fmaf(acc[r], SC2, lb));
    }
  };
  // Dense store: instruction i writes q-row 4h+i entirely; lane l covers
  // float offset l*4 of the row's 1KB slice (k = l>>1, heads = (l&1)*4..+3).
  auto storeStep = [&](int tt, int buf) {
    const int kl = lane >> 1;
    const int h0 = (lane & 1) * 4;
    const int k0 = kh*512 + tt*32;
    #pragma unroll
    for (int i = 0; i < 4; i++) {
      const int q32 = h*4 + i;
      f32x4 v;
      #pragma unroll
      for (int j = 0; j < 4; j++)
        v[j] = Plds[buf][h0 + j][kl][q32];
      *(f32x4*)(attn_out + ((size_t)(n*SEQ + qg*32 + q32)*SEQ + k0 + kl)*NH + h0) = v;
    }
  };
  // LDS-only fence (no vmcnt drain)
  auto ldsBarrier = [&]() {
    asm volatile("s_waitcnt lgkmcnt(0)" ::: "memory");
    __builtin_amdgcn_s_barrier();
  };

  f32x16 acc;
  computeQK(t0, acc);
  scatterP(acc, 0);
  ldsBarrier();

  for (int t = 0; t < 16; ++t) {
    if (t < 15) computeQK((t0 + t + 1) & 15, acc);   // K loads + MFMA (register-only)
    storeStep((t0 + t) & 15, t & 1);                 // dense 1KB-per-instruction stores
    if (t < 15) scatterP(acc, (t + 1) & 1);
    ldsBarrier();
  }

  // ---- ctx merge from cs on kh==0 blocks: flat-indexed, dense 16B/lane ----
  if (kh == 0) {
    #pragma unroll
    for (int i = 0; i < 8; i++) {
      const int chunk = i*512 + tid;        // 0..4095 (64 KB region / 16 B)
      const int q2  = chunk >> 7;           // 0..31
      const int fo  = (chunk & 127) * 4;    // float offset in row
      const int h0  = fo & 7;               // 0 or 4
      const int d   = fo >> 3;              // 0..63
      const int dt  = d >> 5;
      const int rq  = q2 >> 3;
      const int hi2 = (q2 >> 2) & 1;
      const int jj  = q2 & 3;
      const int L   = hi2*32 + (d & 31);
      f32x4 v;
      #pragma unroll
      for (int j = 0; j < 4; j++)
        v[j] = cs[((size_t)((n*NH + h0 + j)*32 + qg))*2048 + ((dt*4 + rq)*64 + L)*4 + jj];
      *(f32x4*)(ctx_out + ((size_t)(n*SEQ + qg*32 + q2))*CIN + fo) = v;
    }
  }
}

// ---------------- launch ----------------
extern "C" void kernel_launch(void* const* d_in, const int* in_sizes, int n_in,
                              void* d_out, int out_size, void* d_ws, size_t ws_size,
                              hipStream_t stream) {
  const float* x  = (const float*)d_in[0];
  const float* wq = (const float*)d_in[1];
  const float* bq = (const float*)d_in[2];
  const float* wk = (const float*)d_in[3];
  const float* bk = (const float*)d_in[4];
  const float* wv = (const float*)d_in[5];
  const float* bv = (const float*)d_in[6];

  float* ctx_out  = (float*)d_out;
  float* attn_out = ctx_out + (size_t)NB * SEQ * CIN;

  const size_t qkv_elems = (size_t)MROWS * CIN;
  u16* qht = (u16*)d_ws;
  u16* qlt = qht + qkv_elems;
  u16* kf  = qlt + qkv_elems;
  u16* vf  = kf  + qkv_elems;
  float* rg = (float*)(vf + qkv_elems);                     // 256 KB
  float* cs = rg + (size_t)NB*NH*SEQ;                       // 16 MB

  dim3 pg_(MROWS / BM, CIN / BN, 3);
  proj_kernel<<<pg_, 256, 0, stream>>>(x, wq, bq, wk, bk, wv, bv, qht, qlt, kf, vf);

  attn_pass1<<<dim3(NB * NH * 8), 512, 0, stream>>>(qht, qlt, kf, vf, rg, cs);

  attn_write<<<dim3(NB * 32 * 2), 512, 0, stream>>>(qht, kf, rg, cs, ctx_out, attn_out);
}